// Round 13
// baseline (15787.009 us; speedup 1.0000x reference)
//
#include <hip/hip_runtime.h>
#include <hip/hip_bf16.h>
#include <math.h>

#define B_   128
#define S_   1024
#define I_   512
#define H_   1024
#define KC   1536
#define NWG  256
#define NTHR 512

typedef __bf16 v8bf __attribute__((ext_vector_type(8)));
typedef float  v4f  __attribute__((ext_vector_type(4)));
typedef unsigned long long ull;

// XOR swizzle on bf16 element index (granule = 8 elems = 16 B).
__device__ __forceinline__ int swz(int row, int e) { return e ^ ((row & 7) << 3); }

__device__ __forceinline__ float sigm(float x) { return 1.f / (1.f + __expf(-x)); }
__device__ __forceinline__ float tanh_fast(float x) {
    const float xc = fminf(fmaxf(x, -15.f), 15.f);
    const float e  = __expf(2.f * xc);
    return (e - 1.f) / (e + 1.f);
}

__device__ __forceinline__ v8bf cvt8(const float4 a, const float4 b) {
    v8bf r;
    r[0] = (__bf16)a.x; r[1] = (__bf16)a.y; r[2] = (__bf16)a.z; r[3] = (__bf16)a.w;
    r[4] = (__bf16)b.x; r[5] = (__bf16)b.y; r[6] = (__bf16)b.z; r[7] = (__bf16)b.w;
    return r;
}

// Pack W_ih||W_hh (fp32) -> Wc bf16 [4096][1536] row-major.
__global__ void lstm_pack(const float* __restrict__ Wih, const float* __restrict__ Whh,
                          __bf16* __restrict__ Wc)
{
    const size_t e = ((size_t)blockIdx.x * 256 + threadIdx.x) * 8;
    const int col = (int)(e / KC);
    const int k   = (int)(e % KC);
    const float4* src = (k < I_) ? (const float4*)&Wih[(size_t)col * I_ + k]
                                 : (const float4*)&Whh[(size_t)col * H_ + (k - I_)];
    const float4 a = src[0], b = src[1];
    *(v8bf*)&Wc[e] = cvt8(a, b);
}

// Persistent LSTM. 256 WGs: bg=(wg&7)>>1 (4 batch groups of 32 rows on an XCD
// pair), cg=((wg>>3)<<1)|(wg&1) (64 col groups of 16 h-cols). 8 waves =
// (gate g, ks). Critical path: K=1024 recurrent GEMM, W_hh resident
// wh[16] v8bf = 64 VGPR/wave (<=96 proven-resident budget, R7). x-part:
// barrier-free mini-GEMM every 2 steps, A direct from seq (L2), W_ih streamed
// behind an opaque pointer (prevents hoist-to-registers = R12's spill cause).
__global__ __launch_bounds__(NTHR, 1) void lstm_persist(
    const float* __restrict__ seq, const int* __restrict__ len,
    const __bf16* __restrict__ Wc,
    const float* __restrict__ bih, const float* __restrict__ bhh,
    float* __restrict__ out, __bf16* __restrict__ hA, __bf16* __restrict__ hB,
    unsigned* __restrict__ flg)
{
    __shared__ __bf16 hpan[32 * 1024];      // h_{t-1}, swizzled (64 KB)
    __shared__ float  glds[4][2][32][17];   // [gate][ks][row][col+pad]
    __shared__ float  gxl[2][32][4][17];    // [step&1][row][gate][col+pad]

    const int wg   = blockIdx.x;
    const int bg   = (wg & 7) >> 1;                // rows bg*32+[0,32)
    const int cg   = ((wg >> 3) << 1) | (wg & 1);  // h-cols cg*16+[0,16)
    const int tid  = threadIdx.x;
    const int lane = tid & 63;
    const int wv   = tid >> 6;
    const int l15  = lane & 15;
    const int q    = lane >> 4;
    const int g    = wv >> 1;    // gate i,f,g,o
    const int ks   = wv & 1;     // main: K-half of 1024; mini: step slot

    const int col = g * H_ + cg * 16 + l15;  // this lane's gate-col
    const float bb = bih[col] + bhh[col];

    // ---- resident W_hh: 16 ktiles (64 VGPR), k = 512 + ks*512 + kt*32 ----
    v8bf wh[16];
    {
        const __bf16* whp = Wc + (size_t)col * KC + 512 + ks * 512 + q * 8;
        #pragma unroll
        for (int kt = 0; kt < 16; ++kt)
            wh[kt] = *(const v8bf*)(whp + kt * 32);
        #pragma unroll
        for (int kt = 0; kt < 16; ++kt) asm volatile("" : "+v"(wh[kt]));
    }

    // ---- update roles: 1 cell/thread (32 rows x 16 cols) ----
    const int urow = tid >> 4;   // [0,32)
    const int ucol = tid & 15;   // [0,16)
    const int gb   = bg * 32 + urow;
    const int gc   = cg * 16 + ucol;
    const int mylen = len[gb];
    float creg = 0.f;

    // ---- mini-GEMM: gx for steps {t0, t0+1}; wave (g, step=ks) ----
    // Barrier-free: A read directly from seq (fp32, L2), B streamed from L2
    // via an opaque pointer (not hoistable), output -> gxl[(t0+ks)&1].
    auto mini_a = [&](int t0) {
        const int tt = t0 + ks;
        const float* x0 = seq + (size_t)(bg * 32 + l15) * (S_ * I_) + (size_t)tt * I_;
        const float* x1 = x0 + (size_t)16 * (S_ * I_);
        const __bf16* wxp = Wc + (size_t)col * KC + q * 8;
        asm volatile("" : "+v"(wxp));   // defeat LICM/CSE on the weight loads
        v4f a0 = {bb, bb, bb, bb};
        v4f a1 = {bb, bb, bb, bb};
        #pragma unroll
        for (int kt = 0; kt < 16; ++kt) {
            const int k = kt * 32 + q * 8;
            const float4* p0 = (const float4*)(x0 + k);
            const float4* p1 = (const float4*)(x1 + k);
            const v8bf af0 = cvt8(p0[0], p0[1]);
            const v8bf af1 = cvt8(p1[0], p1[1]);
            const v8bf wx  = *(const v8bf*)(wxp + kt * 32);
            a0 = __builtin_amdgcn_mfma_f32_16x16x32_bf16(af0, wx, a0, 0, 0, 0);
            a1 = __builtin_amdgcn_mfma_f32_16x16x32_bf16(af1, wx, a1, 0, 0, 0);
        }
        const int sl = tt & 1;
        #pragma unroll
        for (int r = 0; r < 4; ++r) {
            gxl[sl][q * 4 + r][g][l15]      = a0[r];
            gxl[sl][16 + q * 4 + r][g][l15] = a1[r];
        }
    };

    // ---- prologue: gx for steps 0,1 ----
    mini_a(0);

    for (int t = 0; t < S_; ++t) {
        const int buf = t & 1;
        const __bf16* hrd = buf ? hA : hB;   // h_{t-1} (hB zeroed for t=0)
        __bf16*       hwr = buf ? hB : hA;   // h_t

        // ---- poll: all 64 WGs of this bg published h_{t-1} ----
        if (t > 0 && wv == 0) {
            const unsigned* f = flg + bg * 64;
            unsigned v;
            do {
                v = __hip_atomic_load(&f[lane], __ATOMIC_RELAXED,
                                      __HIP_MEMORY_SCOPE_AGENT);
            } while (!__all((int)(v >= (unsigned)t)));
        }
        __syncthreads();  // b1 (also fences gxl/prologue)

        // ---- h_{t-1} -> hpan: linear coalesced 8B atomic loads ----
        {
            const ull* hs = (const ull*)(hrd + (size_t)(bg * 32) * H_);
            ull hv[16];
            #pragma unroll
            for (int j = 0; j < 16; ++j)
                hv[j] = __hip_atomic_load(&hs[tid + 512 * j],
                                          __ATOMIC_RELAXED, __HIP_MEMORY_SCOPE_AGENT);
            #pragma unroll
            for (int j = 0; j < 16; ++j) {
                const int idx = tid + 512 * j;   // [0,8192) ull slots
                const int row = idx >> 8;        // [0,32)
                const int cu  = idx & 255;       // ull col in row
                *(ull*)&hpan[row * 1024 + swz(row, 4 * cu)] = hv[j];
            }
        }
        __syncthreads();  // b2

        // ---- recurrent MFMA: 16 ktiles x 2 M-tiles, resident wh ----
        v4f acc0 = {0.f, 0.f, 0.f, 0.f};
        v4f acc1 = {0.f, 0.f, 0.f, 0.f};
        #pragma unroll
        for (int kt = 0; kt < 16; ++kt) {
            const int e = ks * 512 + kt * 32 + q * 8;
            const v8bf a0 = *(const v8bf*)&hpan[l15 * 1024 + swz(l15, e)];
            const v8bf a1 = *(const v8bf*)&hpan[(16 + l15) * 1024 + swz(16 + l15, e)];
            acc0 = __builtin_amdgcn_mfma_f32_16x16x32_bf16(a0, wh[kt], acc0, 0, 0, 0);
            acc1 = __builtin_amdgcn_mfma_f32_16x16x32_bf16(a1, wh[kt], acc1, 0, 0, 0);
        }

        // ---- exchange partials ----
        #pragma unroll
        for (int r = 0; r < 4; ++r) {
            glds[g][ks][q * 4 + r][l15]      = acc0[r];
            glds[g][ks][16 + q * 4 + r][l15] = acc1[r];
        }
        __syncthreads();  // b3

        // ---- cell update: 2-way ks reduce + gx (has bias) ----
        const float ig = glds[0][0][urow][ucol] + glds[0][1][urow][ucol]
                       + gxl[buf][urow][0][ucol];
        const float fg = glds[1][0][urow][ucol] + glds[1][1][urow][ucol]
                       + gxl[buf][urow][1][ucol];
        const float gg = glds[2][0][urow][ucol] + glds[2][1][urow][ucol]
                       + gxl[buf][urow][2][ucol];
        const float og = glds[3][0][urow][ucol] + glds[3][1][urow][ucol]
                       + gxl[buf][urow][3][ucol];

        const float cn  = sigm(fg) * creg + sigm(ig) * tanh_fast(gg);
        const float hvv = sigm(og) * tanh_fast(cn);
        creg = cn;

        // ---- publish h_t (packed 4B relaxed agent stores) ----
        const unsigned short us = __builtin_bit_cast(unsigned short, (__bf16)hvv);
        const unsigned nb = __shfl_xor((unsigned)us, 1);
        if (!(tid & 1)) {
            const unsigned pair = (unsigned)us | (nb << 16);
            __hip_atomic_store((unsigned*)&hwr[(size_t)gb * H_ + gc], pair,
                               __ATOMIC_RELAXED, __HIP_MEMORY_SCOPE_AGENT);
        }
        if (t == mylen - 1) out[(size_t)gb * H_ + gc] = hvv;

        __syncthreads();  // b4: vmcnt(0) drains h stores; fences gxl reads

        // ---- single-writer epoch flag ----
        if (tid == 0)
            __hip_atomic_store(&flg[bg * 64 + cg], (unsigned)(t + 1),
                               __ATOMIC_RELAXED, __HIP_MEMORY_SCOPE_AGENT);

        // ---- shadow: gx for steps {t+1, t+2} (barrier-free) ----
        if ((t & 1) && (t + 1 < S_)) mini_a(t + 1);
    }
}

extern "C" void kernel_launch(void* const* d_in, const int* in_sizes, int n_in,
                              void* d_out, int out_size, void* d_ws, size_t ws_size,
                              hipStream_t stream) {
    const float* seq = (const float*)d_in[0];
    const int*   len = (const int*)d_in[1];
    const float* Wih = (const float*)d_in[2];
    const float* Whh = (const float*)d_in[3];
    const float* bih = (const float*)d_in[4];
    const float* bhh = (const float*)d_in[5];
    float* out = (float*)d_out;

    char* ws = (char*)d_ws;
    __bf16*   Wc  = (__bf16*)ws;                          // 12,582,912 B
    __bf16*   hA  = (__bf16*)(ws + 12582912);             //    262,144 B
    __bf16*   hB  = (__bf16*)(ws + 12845056);             //    262,144 B
    unsigned* flg = (unsigned*)(ws + 13107200);           //      1,024 B

    hipMemsetAsync(hA, 0, 2 * (size_t)B_ * H_ * sizeof(__bf16), stream);  // hA+hB
    hipMemsetAsync(flg, 0, 4 * 64 * sizeof(unsigned), stream);

    lstm_pack<<<dim3(3072), dim3(256), 0, stream>>>(Wih, Whh, Wc);

    void* args[] = {(void*)&seq, (void*)&len, (void*)&Wc, (void*)&bih,
                    (void*)&bhh, (void*)&out, (void*)&hA, (void*)&hB, (void*)&flg};
    hipError_t e = hipLaunchCooperativeKernel((void*)lstm_persist, dim3(NWG),
                                              dim3(NTHR), args, 0, stream);
    if (e != hipSuccess) {
        lstm_persist<<<dim3(NWG), dim3(NTHR), 0, stream>>>(seq, len, Wc, bih,
                                                           bhh, out, hA, hB, flg);
    }
}

// Round 14
// 3384.953 us; speedup vs baseline: 4.6639x; 4.6639x over previous
//
#include <hip/hip_runtime.h>
#include <hip/hip_bf16.h>
#include <math.h>

#define B_   128
#define S_   1024
#define I_   512
#define H_   1024
#define KC   1536
#define NWG  256
#define NTHR 512
#define LDA  1544   // LDS A-panel row stride (1536 + 8 pad)

typedef __bf16 v8bf __attribute__((ext_vector_type(8)));
typedef float  v4f  __attribute__((ext_vector_type(4)));

__device__ __forceinline__ v8bf cvt8(const float4 a, const float4 b) {
    v8bf r;
    r[0] = (__bf16)a.x; r[1] = (__bf16)a.y; r[2] = (__bf16)a.z; r[3] = (__bf16)a.w;
    r[4] = (__bf16)b.x; r[5] = (__bf16)b.y; r[6] = (__bf16)b.z; r[7] = (__bf16)b.w;
    return r;
}

__device__ __forceinline__ float sigm(float x) { return 1.f / (1.f + __expf(-x)); }
__device__ __forceinline__ float tanh_fast(float x) {
    const float xc = fminf(fmaxf(x, -15.f), 15.f);
    const float e  = __expf(2.f * xc);
    return (e - 1.f) / (e + 1.f);
}

// Pack W_ih||W_hh (fp32) -> Wpk bf16 in MFMA-FRAGMENT ORDER so the per-step
// weight re-stream is perfectly coalesced (1 KB contiguous per wave load).
// Block layout: bIdx = ((cg*4 + g)*2 + ks)*48 + j*2 + c, block = 64 lanes x
// 8 bf16 (lane-major). j<8: x-region k = ks*256 + j*32 + q*8; j>=8: h-region
// k = 512 + ks*512 + (j-8)*32 + q*8. col = g*1024 + cg*32 + c*16 + l15.
__global__ void lstm_pack(const float* __restrict__ Wih, const float* __restrict__ Whh,
                          __bf16* __restrict__ Wpk)
{
    const int id   = blockIdx.x * 256 + threadIdx.x;   // [0, 786432)
    const int lane = id & 63;
    const int bIdx = id >> 6;
    const int c    = bIdx & 1;
    const int j    = (bIdx >> 1) % 24;
    const int rest = bIdx / 48;          // (cg*4 + g)*2 + ks
    const int ks   = rest & 1;
    const int g    = (rest >> 1) & 3;
    const int cg   = rest >> 3;
    const int l15  = lane & 15;
    const int q    = lane >> 4;

    const int col = g * H_ + cg * 32 + c * 16 + l15;
    const int k   = (j < 8) ? (ks * 256 + j * 32 + q * 8)
                            : (512 + ks * 512 + (j - 8) * 32 + q * 8);
    const float4* src = (k < I_) ? (const float4*)&Wih[(size_t)col * I_ + k]
                                 : (const float4*)&Whh[(size_t)col * H_ + (k - I_)];
    const float4 a = src[0], b = src[1];
    Wpk[(size_t)bIdx * 512 + lane * 8 + 0] = (__bf16)a.x;
    Wpk[(size_t)bIdx * 512 + lane * 8 + 1] = (__bf16)a.y;
    Wpk[(size_t)bIdx * 512 + lane * 8 + 2] = (__bf16)a.z;
    Wpk[(size_t)bIdx * 512 + lane * 8 + 3] = (__bf16)a.w;
    Wpk[(size_t)bIdx * 512 + lane * 8 + 4] = (__bf16)b.x;
    Wpk[(size_t)bIdx * 512 + lane * 8 + 5] = (__bf16)b.y;
    Wpk[(size_t)bIdx * 512 + lane * 8 + 6] = (__bf16)b.z;
    Wpk[(size_t)bIdx * 512 + lane * 8 + 7] = (__bf16)b.w;
}

// Persistent LSTM — R6 structure verbatim (proven 3348 us) with the single
// change: weight loads come from the fragment-ordered Wpk (coalesced remat
// stream from L2) instead of scattered row-major Wc. No residency pins.
__global__ __launch_bounds__(NTHR, 1) void lstm_persist(
    const float* __restrict__ seq, const int* __restrict__ len,
    const __bf16* __restrict__ Wpk,
    const float* __restrict__ bih, const float* __restrict__ bhh,
    float* __restrict__ out, __bf16* __restrict__ hA, __bf16* __restrict__ hB,
    unsigned* __restrict__ cnt)
{
    __shared__ __bf16 Apan[16 * LDA];        // [batch 16][x 512 | h 1024]
    __shared__ float  glds[4][2][16][33];    // [gate][k-half][batch][hcol+pad]

    const int wg   = blockIdx.x;
    const int bg   = wg & 7;     // batch group: rows bg*16+[0,16)  (XCD-local)
    const int cg   = wg >> 3;    // h-col group: cols cg*32+[0,32)
    const int tid  = threadIdx.x;
    const int lane = tid & 63;
    const int wv   = tid >> 6;
    const int l15  = lane & 15;
    const int q    = lane >> 4;
    const int gate = wv >> 1;
    const int ks   = wv & 1;

    const int n0   = gate * H_ + cg * 32;
    const int col0 = n0 + l15;
    const int col1 = n0 + 16 + l15;

    // ---- weights: fragment-ordered base for this wave (coalesced loads) ----
    const __bf16* wb = Wpk + (size_t)(((cg * 4 + gate) * 2 + ks) * 48) * 512
                     + lane * 8;
    v8bf wx0[8], wx1[8], wh0[16], wh1[16];
    #pragma unroll
    for (int j = 0; j < 8; ++j) {
        wx0[j] = *(const v8bf*)(wb + (size_t)j * 1024);
        wx1[j] = *(const v8bf*)(wb + (size_t)j * 1024 + 512);
    }
    #pragma unroll
    for (int j = 0; j < 16; ++j) {
        wh0[j] = *(const v8bf*)(wb + (size_t)(8 + j) * 1024);
        wh1[j] = *(const v8bf*)(wb + (size_t)(8 + j) * 1024 + 512);
    }
    const float b0 = ks ? 0.f : (bih[col0] + bhh[col0]);
    const float b1 = ks ? 0.f : (bih[col1] + bhh[col1]);

    // ---- per-thread cell ----
    const int cb = tid >> 5;                 // [0,16)
    const int cc = tid & 31;                 // [0,32)
    const int gb = bg * 16 + cb;
    const int gc = cg * 32 + cc;
    const int mylen = len[gb];
    float creg = 0.f;

    for (int t = 0; t < S_; ++t) {
        const __bf16* hrd = (t & 1) ? hA : hB;   // h_{t-1}
        __bf16*       hwr = (t & 1) ? hB : hA;   // h_t

        // ---- stage x_t into LDS (overlaps the poll below) ----
        {
            const float4* xp = (const float4*)&seq[((size_t)gb * S_ + (size_t)t) * I_ + cc * 16];
            v8bf* dx = (v8bf*)&Apan[cb * LDA + cc * 16];
            const float4 x0 = xp[0], x1 = xp[1];
            dx[0] = cvt8(x0, x1);
            const float4 x2 = xp[2], x3 = xp[3];
            dx[1] = cvt8(x2, x3);
        }

        // ---- wait for h_{t-1} from all 32 WGs of this batch group ----
        if (t > 0 && tid == 0) {
            const unsigned* c0 = cnt + ((size_t)(t - 1) * 4) * 32 + bg;
            unsigned s;
            do {
                s  = __hip_atomic_load(c0 +  0, __ATOMIC_RELAXED, __HIP_MEMORY_SCOPE_AGENT);
                s += __hip_atomic_load(c0 + 32, __ATOMIC_RELAXED, __HIP_MEMORY_SCOPE_AGENT);
                s += __hip_atomic_load(c0 + 64, __ATOMIC_RELAXED, __HIP_MEMORY_SCOPE_AGENT);
                s += __hip_atomic_load(c0 + 96, __ATOMIC_RELAXED, __HIP_MEMORY_SCOPE_AGENT);
            } while (s < 32u);
        }
        __syncthreads();  // b1: x staged, h_{t-1} published

        // ---- issue h loads (coherent 8B atomics), hide under x-MFMA ----
        unsigned long long hv8[8];
        {
            const unsigned long long* hs =
                (const unsigned long long*)(hrd + (size_t)(bg * 16) * H_);
            #pragma unroll
            for (int j = 0; j < 8; ++j)
                hv8[j] = __hip_atomic_load(&hs[cb * 256 + cc + 32 * j],
                                           __ATOMIC_RELAXED, __HIP_MEMORY_SCOPE_AGENT);
        }

        // ---- x-part MFMA (independent of h) ----
        v4f acc0 = {0.f, 0.f, 0.f, 0.f};
        v4f acc1 = {0.f, 0.f, 0.f, 0.f};
        {
            const __bf16* ap = &Apan[l15 * LDA + ks * 256 + q * 8];
            #pragma unroll
            for (int j = 0; j < 8; ++j) {
                const v8bf a = *(const v8bf*)(ap + j * 32);
                acc0 = __builtin_amdgcn_mfma_f32_16x16x32_bf16(a, wx0[j], acc0, 0, 0, 0);
                acc1 = __builtin_amdgcn_mfma_f32_16x16x32_bf16(a, wx1[j], acc1, 0, 0, 0);
            }
        }

        // ---- land h into LDS ----
        #pragma unroll
        for (int j = 0; j < 8; ++j)
            *(unsigned long long*)&Apan[cb * LDA + I_ + 4 * (cc + 32 * j)] = hv8[j];
        __syncthreads();  // b2: h panel ready

        // ---- h-part MFMA ----
        {
            const __bf16* ap = &Apan[l15 * LDA + I_ + ks * 512 + q * 8];
            #pragma unroll
            for (int j = 0; j < 16; ++j) {
                const v8bf a = *(const v8bf*)(ap + j * 32);
                acc0 = __builtin_amdgcn_mfma_f32_16x16x32_bf16(a, wh0[j], acc0, 0, 0, 0);
                acc1 = __builtin_amdgcn_mfma_f32_16x16x32_bf16(a, wh1[j], acc1, 0, 0, 0);
            }
        }

        // ---- exchange gate pre-activations ----
        #pragma unroll
        for (int r = 0; r < 4; ++r) {
            glds[gate][ks][q * 4 + r][l15]      = acc0[r] + b0;
            glds[gate][ks][q * 4 + r][16 + l15] = acc1[r] + b1;
        }
        __syncthreads();  // b3

        // ---- cell update ----
        const float ig = glds[0][0][cb][cc] + glds[0][1][cb][cc];
        const float fg = glds[1][0][cb][cc] + glds[1][1][cb][cc];
        const float gg = glds[2][0][cb][cc] + glds[2][1][cb][cc];
        const float og = glds[3][0][cb][cc] + glds[3][1][cb][cc];

        const float cn = sigm(fg) * creg + sigm(ig) * tanh_fast(gg);
        const float hv = sigm(og) * tanh_fast(cn);
        creg = cn;

        // ---- publish h_t (packed 4B relaxed agent stores) ----
        const __bf16 hb = (__bf16)hv;
        const unsigned short us = __builtin_bit_cast(unsigned short, hb);
        const unsigned nb = __shfl_xor((unsigned)us, 1);
        if ((lane & 1) == 0) {
            const unsigned pair = (unsigned)us | (nb << 16);
            __hip_atomic_store((unsigned*)&hwr[(size_t)gb * H_ + gc], pair,
                               __ATOMIC_RELAXED, __HIP_MEMORY_SCOPE_AGENT);
        }
        if (t == mylen - 1) out[(size_t)gb * H_ + gc] = hv;

        __syncthreads();  // b4: drains h stores (vmcnt 0 before barrier)
        if (tid == 0)
            __hip_atomic_fetch_add(cnt + ((size_t)t * 4 + (cg & 3)) * 32 + bg, 1u,
                                   __ATOMIC_RELAXED, __HIP_MEMORY_SCOPE_AGENT);
    }
}

extern "C" void kernel_launch(void* const* d_in, const int* in_sizes, int n_in,
                              void* d_out, int out_size, void* d_ws, size_t ws_size,
                              hipStream_t stream) {
    const float* seq = (const float*)d_in[0];
    const int*   len = (const int*)d_in[1];
    const float* Wih = (const float*)d_in[2];
    const float* Whh = (const float*)d_in[3];
    const float* bih = (const float*)d_in[4];
    const float* bhh = (const float*)d_in[5];
    float* out = (float*)d_out;

    char* ws = (char*)d_ws;
    __bf16*   Wpk = (__bf16*)ws;                          // 12,582,912 B
    __bf16*   hA  = (__bf16*)(ws + 12582912);             //    262,144 B
    __bf16*   hB  = (__bf16*)(ws + 12845056);             //    262,144 B
    unsigned* cnt = (unsigned*)(ws + 13107200);           //    524,288 B

    hipMemsetAsync(hA, 0, 2 * (size_t)B_ * H_ * sizeof(__bf16), stream);  // hA+hB
    hipMemsetAsync(cnt, 0, (size_t)S_ * 4 * 32 * sizeof(unsigned), stream);

    lstm_pack<<<dim3(3072), dim3(256), 0, stream>>>(Wih, Whh, Wpk);

    void* args[] = {(void*)&seq, (void*)&len, (void*)&Wpk, (void*)&bih,
                    (void*)&bhh, (void*)&out, (void*)&hA, (void*)&hB, (void*)&cnt};
    hipError_t e = hipLaunchCooperativeKernel((void*)lstm_persist, dim3(NWG),
                                              dim3(NTHR), args, 0, stream);
    if (e != hipSuccess) {
        lstm_persist<<<dim3(NWG), dim3(NTHR), 0, stream>>>(seq, len, Wpk, bih,
                                                           bhh, out, hA, hB, cnt);
    }
}